// Round 4
// baseline (241.931 us; speedup 1.0000x reference)
//
#include <hip/hip_runtime.h>

typedef __fp16   fp16x2  __attribute__((ext_vector_type(2)));
typedef _Float16 half4   __attribute__((ext_vector_type(4)));
typedef float    floatx4 __attribute__((ext_vector_type(4)));

// tanh(z) = 1 - 2/(2^(K*z)+1), K = 2*log2(e) folded into all weights/biases.
// One trans op (exp2); the division is software Newton on the full-rate VALU:
// seed via exponent bit-trick (~10% err), 2 fma-form iterations -> <=1.4e-4 rel.
__device__ __forceinline__ float act_pre(float a) {
    float t = __builtin_amdgcn_exp2f(a);
    float d = t + 1.0f;                       // d in [1, ~2^58] -- seed valid, no inf
    float r = __int_as_float(0x7EF127EA - __float_as_int(d));
    r = fmaf(fmaf(-d, r, 1.0f), r, r);        // Newton 1: err ~1e-2
    r = fmaf(fmaf(-d, r, 1.0f), r, r);        // Newton 2: err ~1e-4
    return fmaf(-2.0f, r, 1.0f);
}

__device__ __forceinline__ half4 mk4(fp16x2 lo, fp16x2 hi) {
    union { fp16x2 h2[2]; half4 h4; } u;
    u.h2[0] = lo; u.h2[1] = hi;
    return u.h4;
}

struct NetW {
    float   W0c[4][4];  // layer-0 live cols, pre-scaled by K
    float   c1[4];      // K * (b0 + W0[:,4:16] . extra)
    half4   aW[3];      // layers 1..3 A-frags, pre-scaled by K
    floatx4 bC[3];      // biases as C-frags, pre-scaled by K
    half4   aWf;        // final-layer weights K*Wf[k], replicated over rows
};

__global__ __launch_bounds__(256, 4) void automaton_kernel(
    const float* __restrict__ x, const float* __restrict__ Ws,
    const float* __restrict__ bs, const float* __restrict__ Wf,
    const float* __restrict__ bf, const float* __restrict__ extra,
    float* __restrict__ out, int n_groups)
{
    const float K = 2.885390081777927f;  // 2*log2(e)
    const int tid   = blockIdx.x * blockDim.x + threadIdx.x;
    const int wave  = tid >> 6;
    const int lane  = threadIdx.x & 63;
    const int col   = lane & 15;
    const int sub   = lane >> 4;
    const int obase = sub * 4;

    NetW w;
    float ex[12];
#pragma unroll
    for (int j = 0; j < 12; ++j) ex[j] = extra[j];

    // Layer 0: live cols (scaled by K), fold extra+bias into c1 (scaled by K)
#pragma unroll
    for (int e = 0; e < 4; ++e) {
        const float* row = Ws + (obase + e) * 16;
        floatx4 r0 = *(const floatx4*)(row);
        floatx4 r1 = *(const floatx4*)(row + 4);
        floatx4 r2 = *(const floatx4*)(row + 8);
        floatx4 r3 = *(const floatx4*)(row + 12);
#pragma unroll
        for (int j = 0; j < 4; ++j) w.W0c[e][j] = r0[j] * K;
        float c = bs[obase + e];
#pragma unroll
        for (int j = 0; j < 4; ++j) c = fmaf(r1[j], ex[j], c);
#pragma unroll
        for (int j = 0; j < 4; ++j) c = fmaf(r2[j], ex[4 + j], c);
#pragma unroll
        for (int j = 0; j < 4; ++j) c = fmaf(r3[j], ex[8 + j], c);
        w.c1[e] = c * K;
    }

    // Hidden layers 1..3 as A-frags + bias C-frags, all pre-scaled by K
#pragma unroll
    for (int L = 0; L < 3; ++L) {
        floatx4 wr = *(const floatx4*)(Ws + (L + 1) * 256 + col * 16 + obase);
        half4 a;
#pragma unroll
        for (int e = 0; e < 4; ++e) a[e] = (_Float16)(wr[e] * K);
        w.aW[L] = a;
        floatx4 bb = *(const floatx4*)(bs + (L + 1) * 16 + obase);
#pragma unroll
        for (int e = 0; e < 4; ++e) bb[e] *= K;
        w.bC[L] = bb;
    }
    {
        // Reduction MFMA: A[o,k] = K*Wf[k] for every o -> D = K*Wf.(t1-t2) in all lanes
        floatx4 wf = *(const floatx4*)(Wf + obase);
        half4 a;
#pragma unroll
        for (int e = 0; e < 4; ++e) a[e] = (_Float16)(wf[e] * K);
        w.aWf = a;
    }

    const int g      = wave * 16 + col;
    const bool valid = (g < n_groups);
    const int gl     = valid ? g : (n_groups - 1);
    const float* xp  = x + (size_t)gl * 104;   // 26 channels * 4 floats

    const floatx4 zeroC = {0.f, 0.f, 0.f, 0.f};
    float acc = 0.0f;
    floatx4 xv = *(const floatx4*)(xp);
#pragma unroll 2
    for (int c = 0; c < 26; ++c) {
        floatx4 xn = (c < 25) ? *(const floatx4*)(xp + (c + 1) * 4) : xv;

        // Layer 0 for both nets (net2 = rotated channels), f32 FMA
        half4 hb1, hb2;
        {
            float z1[4], z2[4];
#pragma unroll
            for (int e = 0; e < 4; ++e) {
                float a1 = w.c1[e];
                a1 = fmaf(w.W0c[e][0], xv[0], a1);
                a1 = fmaf(w.W0c[e][1], xv[1], a1);
                a1 = fmaf(w.W0c[e][2], xv[2], a1);
                a1 = fmaf(w.W0c[e][3], xv[3], a1);
                float a2 = w.c1[e];
                a2 = fmaf(w.W0c[e][0], xv[2], a2);
                a2 = fmaf(w.W0c[e][1], xv[3], a2);
                a2 = fmaf(w.W0c[e][2], xv[0], a2);
                a2 = fmaf(w.W0c[e][3], xv[1], a2);
                z1[e] = a1; z2[e] = a2;
            }
            hb1 = mk4(__builtin_amdgcn_cvt_pkrtz(act_pre(z1[0]), act_pre(z1[1])),
                      __builtin_amdgcn_cvt_pkrtz(act_pre(z1[2]), act_pre(z1[3])));
            hb2 = mk4(__builtin_amdgcn_cvt_pkrtz(act_pre(z2[0]), act_pre(z2[1])),
                      __builtin_amdgcn_cvt_pkrtz(act_pre(z2[2]), act_pre(z2[3])));
        }

        // Hidden layers 1,2: MFMA -> packed tanh -> f16 B-frag (layout identity)
#pragma unroll
        for (int L = 0; L < 2; ++L) {
            floatx4 d1 = __builtin_amdgcn_mfma_f32_16x16x16f16(w.aW[L], hb1, w.bC[L], 0, 0, 0);
            floatx4 d2 = __builtin_amdgcn_mfma_f32_16x16x16f16(w.aW[L], hb2, w.bC[L], 0, 0, 0);
            hb1 = mk4(__builtin_amdgcn_cvt_pkrtz(act_pre(d1[0]), act_pre(d1[1])),
                      __builtin_amdgcn_cvt_pkrtz(act_pre(d1[2]), act_pre(d1[3])));
            hb2 = mk4(__builtin_amdgcn_cvt_pkrtz(act_pre(d2[0]), act_pre(d2[1])),
                      __builtin_amdgcn_cvt_pkrtz(act_pre(d2[2]), act_pre(d2[3])));
        }

        // Hidden layer 3 + fused final 16->1 via reduction MFMA (bf cancels in f1-f2)
        {
            floatx4 d1 = __builtin_amdgcn_mfma_f32_16x16x16f16(w.aW[2], hb1, w.bC[2], 0, 0, 0);
            floatx4 d2 = __builtin_amdgcn_mfma_f32_16x16x16f16(w.aW[2], hb2, w.bC[2], 0, 0, 0);
            float s0 = act_pre(d1[0]) - act_pre(d2[0]);
            float s1 = act_pre(d1[1]) - act_pre(d2[1]);
            float s2 = act_pre(d1[2]) - act_pre(d2[2]);
            float s3 = act_pre(d1[3]) - act_pre(d2[3]);
            half4 sb = mk4(__builtin_amdgcn_cvt_pkrtz(s0, s1),
                           __builtin_amdgcn_cvt_pkrtz(s2, s3));
            floatx4 dr = __builtin_amdgcn_mfma_f32_16x16x16f16(w.aWf, sb, zeroC, 0, 0, 0);
            acc += act_pre(dr[0]);
        }
        xv = xn;
    }
    if (lane < 16 && valid)
        out[g] = acc * 0.041875863808787856f;  // ONE_OVER_DIFF_TOT * DIFF_Q
}

extern "C" void kernel_launch(void* const* d_in, const int* in_sizes, int n_in,
                              void* d_out, int out_size, void* d_ws, size_t ws_size,
                              hipStream_t stream) {
    const float* x  = (const float*)d_in[0];
    const float* Ws = (const float*)d_in[1];
    const float* bs = (const float*)d_in[2];
    const float* Wf = (const float*)d_in[3];
    const float* bf = (const float*)d_in[4];
    const float* ex = (const float*)d_in[5];
    float* out = (float*)d_out;

    const int n_groups = out_size;              // B*N = 262144
    const int waves    = (n_groups + 15) / 16;  // 16 groups per wave
    const int blocks   = (waves + 3) / 4;       // 4 waves per block
    automaton_kernel<<<blocks, 256, 0, stream>>>(x, Ws, bs, Wf, bf, ex, out, n_groups);
}

// Round 5
// 219.030 us; speedup vs baseline: 1.1046x; 1.1046x over previous
//
#include <hip/hip_runtime.h>

typedef __fp16   fp16x2  __attribute__((ext_vector_type(2)));
typedef _Float16 half4   __attribute__((ext_vector_type(4)));
typedef float    floatx4 __attribute__((ext_vector_type(4)));

// tanh(z) = 1 - 2/(2^(K*z)+1), K = 2*log2(e) folded into all weights/biases.
// Single act (used once per c-step): hardware exp2 + hardware rcp.
__device__ __forceinline__ float act_pre(float a) {
    float t = __builtin_amdgcn_exp2f(a);
    float r = __builtin_amdgcn_rcpf(t + 1.0f);
    return fmaf(-2.0f, r, 1.0f);
}

// Batched act for 8 pre-scaled pre-activations: 8x exp2 + ONE rcp via
// Montgomery batch inversion (prefix products + walk-back).
// Clamp a<=15 => d<=2^15+1 => prod of 8 <= 2^120.1 (no overflow); clamp error
// on tanh is 2^-14 (~6e-5), invisible vs the f16 activation rounding.
__device__ __forceinline__ void tanh8(const float* z, float* th) {
    float d[8];
#pragma unroll
    for (int i = 0; i < 8; ++i)
        d[i] = __builtin_amdgcn_exp2f(fminf(z[i], 15.0f)) + 1.0f;
    float p[8];
    p[0] = d[0];
#pragma unroll
    for (int i = 1; i < 8; ++i) p[i] = p[i - 1] * d[i];
    float r = __builtin_amdgcn_rcpf(p[7]);
#pragma unroll
    for (int i = 7; i >= 1; --i) {
        th[i] = fmaf(-2.0f, r * p[i - 1], 1.0f);  // 1/d_i = r_i * p_{i-1}
        r *= d[i];                                 // r_{i-1} = 1/p_{i-1}
    }
    th[0] = fmaf(-2.0f, r, 1.0f);
}

__device__ __forceinline__ half4 mk4(fp16x2 lo, fp16x2 hi) {
    union { fp16x2 h2[2]; half4 h4; } u;
    u.h2[0] = lo; u.h2[1] = hi;
    return u.h4;
}

struct NetW {
    float   W0c[4][4];  // layer-0 live cols, pre-scaled by K
    float   c1[4];      // K * (b0 + W0[:,4:16] . extra)
    half4   aW[3];      // layers 1..3 A-frags, pre-scaled by K
    floatx4 bC[3];      // biases as C-frags, pre-scaled by K
    half4   aWf;        // final-layer weights K*Wf[k], replicated over rows
};

__global__ __launch_bounds__(256, 4) void automaton_kernel(
    const float* __restrict__ x, const float* __restrict__ Ws,
    const float* __restrict__ bs, const float* __restrict__ Wf,
    const float* __restrict__ bf, const float* __restrict__ extra,
    float* __restrict__ out, int n_groups)
{
    const float K = 2.885390081777927f;  // 2*log2(e)
    const int tid   = blockIdx.x * blockDim.x + threadIdx.x;
    const int wave  = tid >> 6;
    const int lane  = threadIdx.x & 63;
    const int col   = lane & 15;
    const int sub   = lane >> 4;
    const int obase = sub * 4;

    NetW w;
    float ex[12];
#pragma unroll
    for (int j = 0; j < 12; ++j) ex[j] = extra[j];

    // Layer 0: live cols (scaled by K), fold extra+bias into c1 (scaled by K)
#pragma unroll
    for (int e = 0; e < 4; ++e) {
        const float* row = Ws + (obase + e) * 16;
        floatx4 r0 = *(const floatx4*)(row);
        floatx4 r1 = *(const floatx4*)(row + 4);
        floatx4 r2 = *(const floatx4*)(row + 8);
        floatx4 r3 = *(const floatx4*)(row + 12);
#pragma unroll
        for (int j = 0; j < 4; ++j) w.W0c[e][j] = r0[j] * K;
        float c = bs[obase + e];
#pragma unroll
        for (int j = 0; j < 4; ++j) c = fmaf(r1[j], ex[j], c);
#pragma unroll
        for (int j = 0; j < 4; ++j) c = fmaf(r2[j], ex[4 + j], c);
#pragma unroll
        for (int j = 0; j < 4; ++j) c = fmaf(r3[j], ex[8 + j], c);
        w.c1[e] = c * K;
    }

    // Hidden layers 1..3 as A-frags + bias C-frags, all pre-scaled by K
#pragma unroll
    for (int L = 0; L < 3; ++L) {
        floatx4 wr = *(const floatx4*)(Ws + (L + 1) * 256 + col * 16 + obase);
        half4 a;
#pragma unroll
        for (int e = 0; e < 4; ++e) a[e] = (_Float16)(wr[e] * K);
        w.aW[L] = a;
        floatx4 bb = *(const floatx4*)(bs + (L + 1) * 16 + obase);
#pragma unroll
        for (int e = 0; e < 4; ++e) bb[e] *= K;
        w.bC[L] = bb;
    }
    {
        // Reduction MFMA: A[o,k] = K*Wf[k] for every o -> D = K*Wf.(t1-t2) in all lanes
        floatx4 wf = *(const floatx4*)(Wf + obase);
        half4 a;
#pragma unroll
        for (int e = 0; e < 4; ++e) a[e] = (_Float16)(wf[e] * K);
        w.aWf = a;
    }

    const int g      = wave * 16 + col;
    const bool valid = (g < n_groups);
    const int gl     = valid ? g : (n_groups - 1);
    const float* xp  = x + (size_t)gl * 104;   // 26 channels * 4 floats

    const floatx4 zeroC = {0.f, 0.f, 0.f, 0.f};
    float acc = 0.0f;
    floatx4 xv = *(const floatx4*)(xp);
#pragma unroll 2
    for (int c = 0; c < 26; ++c) {
        floatx4 xn = (c < 25) ? *(const floatx4*)(xp + (c + 1) * 4) : xv;

        // Layer 0 for both nets (net2 = rotated channels), f32 FMA
        half4 hb1, hb2;
        {
            float z[8], th[8];
#pragma unroll
            for (int e = 0; e < 4; ++e) {
                float a1 = w.c1[e];
                a1 = fmaf(w.W0c[e][0], xv[0], a1);
                a1 = fmaf(w.W0c[e][1], xv[1], a1);
                a1 = fmaf(w.W0c[e][2], xv[2], a1);
                a1 = fmaf(w.W0c[e][3], xv[3], a1);
                float a2 = w.c1[e];
                a2 = fmaf(w.W0c[e][0], xv[2], a2);
                a2 = fmaf(w.W0c[e][1], xv[3], a2);
                a2 = fmaf(w.W0c[e][2], xv[0], a2);
                a2 = fmaf(w.W0c[e][3], xv[1], a2);
                z[e] = a1; z[4 + e] = a2;
            }
            tanh8(z, th);
            hb1 = mk4(__builtin_amdgcn_cvt_pkrtz(th[0], th[1]),
                      __builtin_amdgcn_cvt_pkrtz(th[2], th[3]));
            hb2 = mk4(__builtin_amdgcn_cvt_pkrtz(th[4], th[5]),
                      __builtin_amdgcn_cvt_pkrtz(th[6], th[7]));
        }

        // Hidden layers 1,2: MFMA -> batched tanh -> f16 B-frag (layout identity)
#pragma unroll
        for (int L = 0; L < 2; ++L) {
            floatx4 d1 = __builtin_amdgcn_mfma_f32_16x16x16f16(w.aW[L], hb1, w.bC[L], 0, 0, 0);
            floatx4 d2 = __builtin_amdgcn_mfma_f32_16x16x16f16(w.aW[L], hb2, w.bC[L], 0, 0, 0);
            float z[8], th[8];
#pragma unroll
            for (int e = 0; e < 4; ++e) { z[e] = d1[e]; z[4 + e] = d2[e]; }
            tanh8(z, th);
            hb1 = mk4(__builtin_amdgcn_cvt_pkrtz(th[0], th[1]),
                      __builtin_amdgcn_cvt_pkrtz(th[2], th[3]));
            hb2 = mk4(__builtin_amdgcn_cvt_pkrtz(th[4], th[5]),
                      __builtin_amdgcn_cvt_pkrtz(th[6], th[7]));
        }

        // Hidden layer 3 + fused final 16->1 via reduction MFMA (bf cancels in f1-f2)
        {
            floatx4 d1 = __builtin_amdgcn_mfma_f32_16x16x16f16(w.aW[2], hb1, w.bC[2], 0, 0, 0);
            floatx4 d2 = __builtin_amdgcn_mfma_f32_16x16x16f16(w.aW[2], hb2, w.bC[2], 0, 0, 0);
            float z[8], th[8];
#pragma unroll
            for (int e = 0; e < 4; ++e) { z[e] = d1[e]; z[4 + e] = d2[e]; }
            tanh8(z, th);
            half4 sb = mk4(__builtin_amdgcn_cvt_pkrtz(th[0] - th[4], th[1] - th[5]),
                           __builtin_amdgcn_cvt_pkrtz(th[2] - th[6], th[3] - th[7]));
            floatx4 dr = __builtin_amdgcn_mfma_f32_16x16x16f16(w.aWf, sb, zeroC, 0, 0, 0);
            acc += act_pre(dr[0]);
        }
        xv = xn;
    }
    if (lane < 16 && valid)
        out[g] = acc * 0.041875863808787856f;  // ONE_OVER_DIFF_TOT * DIFF_Q
}

extern "C" void kernel_launch(void* const* d_in, const int* in_sizes, int n_in,
                              void* d_out, int out_size, void* d_ws, size_t ws_size,
                              hipStream_t stream) {
    const float* x  = (const float*)d_in[0];
    const float* Ws = (const float*)d_in[1];
    const float* bs = (const float*)d_in[2];
    const float* Wf = (const float*)d_in[3];
    const float* bf = (const float*)d_in[4];
    const float* ex = (const float*)d_in[5];
    float* out = (float*)d_out;

    const int n_groups = out_size;              // B*N = 262144
    const int waves    = (n_groups + 15) / 16;  // 16 groups per wave
    const int blocks   = (waves + 3) / 4;       // 4 waves per block
    automaton_kernel<<<blocks, 256, 0, stream>>>(x, Ws, bs, Wf, bf, ex, out, n_groups);
}

// Round 6
// 184.412 us; speedup vs baseline: 1.3119x; 1.1877x over previous
//
#include <hip/hip_runtime.h>

typedef __fp16   fp16x2  __attribute__((ext_vector_type(2)));
typedef _Float16 half4   __attribute__((ext_vector_type(4)));
typedef float    floatx4 __attribute__((ext_vector_type(4)));

// Hidden activations are passed to the next layer as the raw reciprocal
//   r = 1/(2^a + 1) in (0,1),   a = K*z pre-scaled by K = 2*log2(e).
// The affine map t = tanh(z) = 1 - 2r is folded into the CONSUMING layer:
//   W'' = -2K*W,   c'' = K*(b + W.1)
// so each hidden act is just {exp2, add, rcp} (no fma, no clamp).
// Saturation is exact: a->+inf => rcp(inf)=0 => t=1; a->-inf => r=1 => t=-1.
__device__ __forceinline__ float ract(float a) {
    return __builtin_amdgcn_rcpf(__builtin_amdgcn_exp2f(a) + 1.0f);
}
// Final act (once per c-step) keeps the explicit tanh form.
__device__ __forceinline__ float act_pre(float a) {
    float r = __builtin_amdgcn_rcpf(__builtin_amdgcn_exp2f(a) + 1.0f);
    return fmaf(-2.0f, r, 1.0f);
}

__device__ __forceinline__ half4 mk4(fp16x2 lo, fp16x2 hi) {
    union { fp16x2 h2[2]; half4 h4; } u;
    u.h2[0] = lo; u.h2[1] = hi;
    return u.h4;
}

struct NetW {
    float   W0c[4][4];  // layer-0 live cols, pre-scaled by K
    float   c1[4];      // K * (b0 + W0[:,4:16] . extra)
    half4   aW[3];      // layers 1..3 A-frags: -2K * W  (consume r-inputs)
    floatx4 bC[3];      // biases as C-frags: K * (b + row-sum(W))
    half4   aWf;        // final reduction A-frag: -2K * Wf (consumes r1-r2)
};

__global__ __launch_bounds__(256, 4) void automaton_kernel(
    const float* __restrict__ x, const float* __restrict__ Ws,
    const float* __restrict__ bs, const float* __restrict__ Wf,
    const float* __restrict__ bf, const float* __restrict__ extra,
    float* __restrict__ out, int n_groups)
{
    const float K = 2.885390081777927f;  // 2*log2(e)
    const int tid   = blockIdx.x * blockDim.x + threadIdx.x;
    const int wave  = tid >> 6;
    const int lane  = threadIdx.x & 63;
    const int col   = lane & 15;
    const int sub   = lane >> 4;
    const int obase = sub * 4;

    NetW w;
    float ex[12];
#pragma unroll
    for (int j = 0; j < 12; ++j) ex[j] = extra[j];

    // Layer 0: live cols (scaled by K), fold extra+bias into c1 (scaled by K)
#pragma unroll
    for (int e = 0; e < 4; ++e) {
        const float* row = Ws + (obase + e) * 16;
        floatx4 r0 = *(const floatx4*)(row);
        floatx4 r1 = *(const floatx4*)(row + 4);
        floatx4 r2 = *(const floatx4*)(row + 8);
        floatx4 r3 = *(const floatx4*)(row + 12);
#pragma unroll
        for (int j = 0; j < 4; ++j) w.W0c[e][j] = r0[j] * K;
        float c = bs[obase + e];
#pragma unroll
        for (int j = 0; j < 4; ++j) c = fmaf(r1[j], ex[j], c);
#pragma unroll
        for (int j = 0; j < 4; ++j) c = fmaf(r2[j], ex[4 + j], c);
#pragma unroll
        for (int j = 0; j < 4; ++j) c = fmaf(r3[j], ex[8 + j], c);
        w.c1[e] = c * K;
    }

    // Hidden layers 1..3: A-frags scaled by -2K (they consume r-inputs);
    // bias C-frags get the folded row-sum: K*(b + sum_k W[o][k]).
#pragma unroll
    for (int L = 0; L < 3; ++L) {
        floatx4 wr = *(const floatx4*)(Ws + (L + 1) * 256 + col * 16 + obase);
        half4 a;
#pragma unroll
        for (int e = 0; e < 4; ++e) a[e] = (_Float16)(wr[e] * (-2.0f * K));
        w.aW[L] = a;
        floatx4 bb = *(const floatx4*)(bs + (L + 1) * 16 + obase);
#pragma unroll
        for (int e = 0; e < 4; ++e) {
            const float* rw = Ws + (L + 1) * 256 + (obase + e) * 16;
            floatx4 s0 = *(const floatx4*)(rw);
            floatx4 s1 = *(const floatx4*)(rw + 4);
            floatx4 s2 = *(const floatx4*)(rw + 8);
            floatx4 s3 = *(const floatx4*)(rw + 12);
            float rs = 0.0f;
#pragma unroll
            for (int j = 0; j < 4; ++j) rs += s0[j] + s1[j] + s2[j] + s3[j];
            bb[e] = (bb[e] + rs) * K;
        }
        w.bC[L] = bb;
    }
    {
        // Reduction MFMA consumes (r1 - r2): A[o,k] = -2K*Wf[k] for every o.
        floatx4 wf = *(const floatx4*)(Wf + obase);
        half4 a;
#pragma unroll
        for (int e = 0; e < 4; ++e) a[e] = (_Float16)(wf[e] * (-2.0f * K));
        w.aWf = a;
    }

    const int g      = wave * 16 + col;
    const bool valid = (g < n_groups);
    const int gl     = valid ? g : (n_groups - 1);
    const float* xp  = x + (size_t)gl * 104;   // 26 channels * 4 floats

    const floatx4 zeroC = {0.f, 0.f, 0.f, 0.f};
    float acc = 0.0f;
    floatx4 xv = *(const floatx4*)(xp);
#pragma unroll 2
    for (int c = 0; c < 26; ++c) {
        floatx4 xn = (c < 25) ? *(const floatx4*)(xp + (c + 1) * 4) : xv;

        // Layer 0 for both nets (net2 = rotated channels), f32 FMA -> r-act
        half4 hb1, hb2;
        {
            float z1[4], z2[4];
#pragma unroll
            for (int e = 0; e < 4; ++e) {
                float a1 = w.c1[e];
                a1 = fmaf(w.W0c[e][0], xv[0], a1);
                a1 = fmaf(w.W0c[e][1], xv[1], a1);
                a1 = fmaf(w.W0c[e][2], xv[2], a1);
                a1 = fmaf(w.W0c[e][3], xv[3], a1);
                float a2 = w.c1[e];
                a2 = fmaf(w.W0c[e][0], xv[2], a2);
                a2 = fmaf(w.W0c[e][1], xv[3], a2);
                a2 = fmaf(w.W0c[e][2], xv[0], a2);
                a2 = fmaf(w.W0c[e][3], xv[1], a2);
                z1[e] = a1; z2[e] = a2;
            }
            hb1 = mk4(__builtin_amdgcn_cvt_pkrtz(ract(z1[0]), ract(z1[1])),
                      __builtin_amdgcn_cvt_pkrtz(ract(z1[2]), ract(z1[3])));
            hb2 = mk4(__builtin_amdgcn_cvt_pkrtz(ract(z2[0]), ract(z2[1])),
                      __builtin_amdgcn_cvt_pkrtz(ract(z2[2]), ract(z2[3])));
        }

        // Hidden layers 1,2: MFMA (weights pre-folded) -> r-act -> f16 B-frag
#pragma unroll
        for (int L = 0; L < 2; ++L) {
            floatx4 d1 = __builtin_amdgcn_mfma_f32_16x16x16f16(w.aW[L], hb1, w.bC[L], 0, 0, 0);
            floatx4 d2 = __builtin_amdgcn_mfma_f32_16x16x16f16(w.aW[L], hb2, w.bC[L], 0, 0, 0);
            hb1 = mk4(__builtin_amdgcn_cvt_pkrtz(ract(d1[0]), ract(d1[1])),
                      __builtin_amdgcn_cvt_pkrtz(ract(d1[2]), ract(d1[3])));
            hb2 = mk4(__builtin_amdgcn_cvt_pkrtz(ract(d2[0]), ract(d2[1])),
                      __builtin_amdgcn_cvt_pkrtz(ract(d2[2]), ract(d2[3])));
        }

        // Hidden layer 3 + fused final 16->1: feed (r1-r2), weights -2K*Wf.
        {
            floatx4 d1 = __builtin_amdgcn_mfma_f32_16x16x16f16(w.aW[2], hb1, w.bC[2], 0, 0, 0);
            floatx4 d2 = __builtin_amdgcn_mfma_f32_16x16x16f16(w.aW[2], hb2, w.bC[2], 0, 0, 0);
            float s0 = ract(d1[0]) - ract(d2[0]);
            float s1 = ract(d1[1]) - ract(d2[1]);
            float s2 = ract(d1[2]) - ract(d2[2]);
            float s3 = ract(d1[3]) - ract(d2[3]);
            half4 sb = mk4(__builtin_amdgcn_cvt_pkrtz(s0, s1),
                           __builtin_amdgcn_cvt_pkrtz(s2, s3));
            floatx4 dr = __builtin_amdgcn_mfma_f32_16x16x16f16(w.aWf, sb, zeroC, 0, 0, 0);
            acc += act_pre(dr[0]);
        }
        xv = xn;
    }
    if (lane < 16 && valid)
        out[g] = acc * 0.041875863808787856f;  // ONE_OVER_DIFF_TOT * DIFF_Q
}

extern "C" void kernel_launch(void* const* d_in, const int* in_sizes, int n_in,
                              void* d_out, int out_size, void* d_ws, size_t ws_size,
                              hipStream_t stream) {
    const float* x  = (const float*)d_in[0];
    const float* Ws = (const float*)d_in[1];
    const float* bs = (const float*)d_in[2];
    const float* Wf = (const float*)d_in[3];
    const float* bf = (const float*)d_in[4];
    const float* ex = (const float*)d_in[5];
    float* out = (float*)d_out;

    const int n_groups = out_size;              // B*N = 262144
    const int waves    = (n_groups + 15) / 16;  // 16 groups per wave
    const int blocks   = (waves + 3) / 4;       // 4 waves per block
    automaton_kernel<<<blocks, 256, 0, stream>>>(x, Ws, bs, Wf, bf, ex, out, n_groups);
}

// Round 7
// 165.558 us; speedup vs baseline: 1.4613x; 1.1139x over previous
//
#include <hip/hip_runtime.h>

typedef __fp16   fp16x2  __attribute__((ext_vector_type(2)));
typedef _Float16 half4   __attribute__((ext_vector_type(4)));
typedef float    floatx4 __attribute__((ext_vector_type(4)));

// Hidden activations are passed to the next layer as the raw reciprocal
//   r = 1/(2^a + 1) in (0,1),   a = K*z pre-scaled by K = 2*log2(e).
// The affine map t = tanh(z) = 1 - 2r is folded into the CONSUMING layer:
//   A'' = f16(-2K*W),  c'' = K*b - 0.5*(A''.1)   (ones-MFMA, exact)
// so each hidden act is just {exp2, add, rcp}.
// Saturation is exact: a->+inf => rcp(inf)=0 => t=1; a->-inf => r=1 => t=-1.
__device__ __forceinline__ float ract(float a) {
    return __builtin_amdgcn_rcpf(__builtin_amdgcn_exp2f(a) + 1.0f);
}
// Final act (once per c-step) keeps the explicit tanh form.
__device__ __forceinline__ float act_pre(float a) {
    float r = __builtin_amdgcn_rcpf(__builtin_amdgcn_exp2f(a) + 1.0f);
    return fmaf(-2.0f, r, 1.0f);
}

__device__ __forceinline__ half4 mk4(fp16x2 lo, fp16x2 hi) {
    union { fp16x2 h2[2]; half4 h4; } u;
    u.h2[0] = lo; u.h2[1] = hi;
    return u.h4;
}

__global__ __launch_bounds__(256, 4) void automaton_kernel(
    const float* __restrict__ x, const float* __restrict__ Ws,
    const float* __restrict__ bs, const float* __restrict__ Wf,
    const float* __restrict__ bf, const float* __restrict__ extra,
    float* __restrict__ out, int n_groups)
{
    const float K = 2.885390081777927f;  // 2*log2(e)
    const int tid   = blockIdx.x * blockDim.x + threadIdx.x;
    const int wave  = tid >> 6;
    const int lane  = threadIdx.x & 63;
    const int col   = lane & 15;
    const int sub   = lane >> 4;
    const int obase = sub * 4;

    const floatx4 zeroC = {0.f, 0.f, 0.f, 0.f};
    const half4   ones  = {(_Float16)1.f, (_Float16)1.f, (_Float16)1.f, (_Float16)1.f};

    float ex[12];
#pragma unroll
    for (int j = 0; j < 12; ++j) ex[j] = extra[j];

    // ---- Layer 0: live cols (scaled by K), fold extra+bias into c1 ----
    float W0c[4][4], c1[4];
#pragma unroll
    for (int e = 0; e < 4; ++e) {
        const float* row = Ws + (obase + e) * 16;
        floatx4 r0 = *(const floatx4*)(row);
        floatx4 r1 = *(const floatx4*)(row + 4);
        floatx4 r2 = *(const floatx4*)(row + 8);
        floatx4 r3 = *(const floatx4*)(row + 12);
#pragma unroll
        for (int j = 0; j < 4; ++j) W0c[e][j] = r0[j] * K;
        float c = bs[obase + e];
#pragma unroll
        for (int j = 0; j < 4; ++j) c = fmaf(r1[j], ex[j], c);
#pragma unroll
        for (int j = 0; j < 4; ++j) c = fmaf(r2[j], ex[4 + j], c);
#pragma unroll
        for (int j = 0; j < 4; ++j) c = fmaf(r3[j], ex[8 + j], c);
        c1[e] = c * K;
    }

    // ---- Hidden layers 1..3: A'' = f16(-2K*W); c'' = K*b - 0.5*(A''.1) ----
    half4 aW0, aW1, aW2, aWf;
    floatx4 bC0, bC1, bC2;
    {
        floatx4 w1 = *(const floatx4*)(Ws + 256 + col * 16 + obase);
        floatx4 w2 = *(const floatx4*)(Ws + 512 + col * 16 + obase);
        floatx4 w3 = *(const floatx4*)(Ws + 768 + col * 16 + obase);
#pragma unroll
        for (int e = 0; e < 4; ++e) {
            aW0[e] = (_Float16)(w1[e] * (-2.0f * K));
            aW1[e] = (_Float16)(w2[e] * (-2.0f * K));
            aW2[e] = (_Float16)(w3[e] * (-2.0f * K));
        }
        // ones-MFMA computes A''.1 exactly into the C/D layout we need
        floatx4 s0 = __builtin_amdgcn_mfma_f32_16x16x16f16(aW0, ones, zeroC, 0, 0, 0);
        floatx4 s1 = __builtin_amdgcn_mfma_f32_16x16x16f16(aW1, ones, zeroC, 0, 0, 0);
        floatx4 s2 = __builtin_amdgcn_mfma_f32_16x16x16f16(aW2, ones, zeroC, 0, 0, 0);
        floatx4 b1 = *(const floatx4*)(bs + 16 + obase);
        floatx4 b2 = *(const floatx4*)(bs + 32 + obase);
        floatx4 b3 = *(const floatx4*)(bs + 48 + obase);
#pragma unroll
        for (int e = 0; e < 4; ++e) {
            bC0[e] = fmaf(-0.5f, s0[e], K * b1[e]);
            bC1[e] = fmaf(-0.5f, s1[e], K * b2[e]);
            bC2[e] = fmaf(-0.5f, s2[e], K * b3[e]);
        }
        // Reduction MFMA consumes (r1 - r2): A[o,k] = -2K*Wf[k] for every o.
        floatx4 wf = *(const floatx4*)(Wf + obase);
#pragma unroll
        for (int e = 0; e < 4; ++e) aWf[e] = (_Float16)(wf[e] * (-2.0f * K));
    }

    const int g      = wave * 16 + col;
    const bool valid = (g < n_groups);
    const int gl     = valid ? g : (n_groups - 1);
    const float* xp  = x + (size_t)gl * 104;   // 26 channels * 4 floats

    float acc = 0.0f;
    floatx4 xv = *(const floatx4*)(xp);
#pragma unroll 2
    for (int c = 0; c < 26; ++c) {
        floatx4 xn = (c < 25) ? *(const floatx4*)(xp + (c + 1) * 4) : xv;

        // Layer 0 for both nets (net2 = rotated channels), f32 FMA -> r-act
        half4 hb1, hb2;
        {
            float z1[4], z2[4];
#pragma unroll
            for (int e = 0; e < 4; ++e) {
                float a1 = c1[e];
                a1 = fmaf(W0c[e][0], xv[0], a1);
                a1 = fmaf(W0c[e][1], xv[1], a1);
                a1 = fmaf(W0c[e][2], xv[2], a1);
                a1 = fmaf(W0c[e][3], xv[3], a1);
                float a2 = c1[e];
                a2 = fmaf(W0c[e][0], xv[2], a2);
                a2 = fmaf(W0c[e][1], xv[3], a2);
                a2 = fmaf(W0c[e][2], xv[0], a2);
                a2 = fmaf(W0c[e][3], xv[1], a2);
                z1[e] = a1; z2[e] = a2;
            }
            hb1 = mk4(__builtin_amdgcn_cvt_pkrtz(ract(z1[0]), ract(z1[1])),
                      __builtin_amdgcn_cvt_pkrtz(ract(z1[2]), ract(z1[3])));
            hb2 = mk4(__builtin_amdgcn_cvt_pkrtz(ract(z2[0]), ract(z2[1])),
                      __builtin_amdgcn_cvt_pkrtz(ract(z2[2]), ract(z2[3])));
        }

        // Hidden layer 1: MFMA (pre-folded) -> r-act -> f16 B-frag
        {
            floatx4 d1 = __builtin_amdgcn_mfma_f32_16x16x16f16(aW0, hb1, bC0, 0, 0, 0);
            floatx4 d2 = __builtin_amdgcn_mfma_f32_16x16x16f16(aW0, hb2, bC0, 0, 0, 0);
            hb1 = mk4(__builtin_amdgcn_cvt_pkrtz(ract(d1[0]), ract(d1[1])),
                      __builtin_amdgcn_cvt_pkrtz(ract(d1[2]), ract(d1[3])));
            hb2 = mk4(__builtin_amdgcn_cvt_pkrtz(ract(d2[0]), ract(d2[1])),
                      __builtin_amdgcn_cvt_pkrtz(ract(d2[2]), ract(d2[3])));
        }
        // Hidden layer 2
        {
            floatx4 d1 = __builtin_amdgcn_mfma_f32_16x16x16f16(aW1, hb1, bC1, 0, 0, 0);
            floatx4 d2 = __builtin_amdgcn_mfma_f32_16x16x16f16(aW1, hb2, bC1, 0, 0, 0);
            hb1 = mk4(__builtin_amdgcn_cvt_pkrtz(ract(d1[0]), ract(d1[1])),
                      __builtin_amdgcn_cvt_pkrtz(ract(d1[2]), ract(d1[3])));
            hb2 = mk4(__builtin_amdgcn_cvt_pkrtz(ract(d2[0]), ract(d2[1])),
                      __builtin_amdgcn_cvt_pkrtz(ract(d2[2]), ract(d2[3])));
        }

        // Hidden layer 3 + fused final 16->1: feed (r1-r2), weights -2K*Wf.
        {
            floatx4 d1 = __builtin_amdgcn_mfma_f32_16x16x16f16(aW2, hb1, bC2, 0, 0, 0);
            floatx4 d2 = __builtin_amdgcn_mfma_f32_16x16x16f16(aW2, hb2, bC2, 0, 0, 0);
            float s0 = ract(d1[0]) - ract(d2[0]);
            float s1 = ract(d1[1]) - ract(d2[1]);
            float s2 = ract(d1[2]) - ract(d2[2]);
            float s3 = ract(d1[3]) - ract(d2[3]);
            half4 sb = mk4(__builtin_amdgcn_cvt_pkrtz(s0, s1),
                           __builtin_amdgcn_cvt_pkrtz(s2, s3));
            floatx4 dr = __builtin_amdgcn_mfma_f32_16x16x16f16(aWf, sb, zeroC, 0, 0, 0);
            acc += act_pre(dr[0]);
        }
        xv = xn;
    }
    if (lane < 16 && valid)
        out[g] = acc * 0.041875863808787856f;  // ONE_OVER_DIFF_TOT * DIFF_Q
}

extern "C" void kernel_launch(void* const* d_in, const int* in_sizes, int n_in,
                              void* d_out, int out_size, void* d_ws, size_t ws_size,
                              hipStream_t stream) {
    const float* x  = (const float*)d_in[0];
    const float* Ws = (const float*)d_in[1];
    const float* bs = (const float*)d_in[2];
    const float* Wf = (const float*)d_in[3];
    const float* bf = (const float*)d_in[4];
    const float* ex = (const float*)d_in[5];
    float* out = (float*)d_out;

    const int n_groups = out_size;              // B*N = 262144
    const int waves    = (n_groups + 15) / 16;  // 16 groups per wave
    const int blocks   = (waves + 3) / 4;       // 4 waves per block
    automaton_kernel<<<blocks, 256, 0, stream>>>(x, Ws, bs, Wf, bf, ex, out, n_groups);
}